// Round 8
// baseline (270.658 us; speedup 1.0000x reference)
//
#include <hip/hip_runtime.h>

// ArcFace loss, MI355X. B=512, D=512, C=64000, s=64, m=0.5.
// R8: normalization FOLDED into epilogue (theta = (x.W)*rsqrt(sum W^2)),
// so raw fp32 W streams HBM->LDS via double-buffered global_load_lds
// INSIDE the K-loop (8 KB tile per 32-K step), repacked in-LDS to bf16
// frag-linear + per-col sumsq accumulated on the fly. The kernel is a
// pure HBM-streaming pipeline: W's 131 MB (>=21 us) is the floor and
// everything else hides under its cadence. A-frags from frag-linear
// xnT in L2 (R5-validated full-line pattern), register-prefetched.

#define B_N 512
#define D_N 512
#define C_N 64000
#define S_SCALE 64.0f
#define MARGIN 0.5f
#define EPS_C 1e-7f
#define NREP 16

typedef unsigned short ushort_t;
typedef __attribute__((ext_vector_type(8))) short short8;   // 8 bf16 (4 VGPRs)
typedef __attribute__((ext_vector_type(4))) float floatx4;  // MFMA acc

__device__ __forceinline__ ushort_t f2bf(float f) {
    unsigned int u = __float_as_uint(f);
    u += 0x7fffu + ((u >> 16) & 1u);  // round-to-nearest-even
    return (ushort_t)(u >> 16);
}

// Normalize x rows -> bf16 in fragment-linear layout:
//   xnT element addr = (kc*512 + row)*8 + j,  kc = k/8 in [0,64), j = k%8.
// Blocks 0..127: 4 rows each. Block 128: zero rowsum replicas.
__global__ void xprep_kernel(const float* __restrict__ x,
                             ushort_t* __restrict__ xnT,
                             float* __restrict__ rowsumR) {
    int b = blockIdx.x;
    int t = threadIdx.x;
    if (b == 128) {
#pragma unroll
        for (int i = 0; i < NREP * B_N / 256; ++i)
            rowsumR[i * 256 + t] = 0.0f;
        return;
    }
    int row  = b * 4 + (t >> 6);
    int lane = t & 63;
    const float4* p = (const float4*)(x + (size_t)row * D_N);
    float4 v0 = p[lane * 2];
    float4 v1 = p[lane * 2 + 1];
    float ss = v0.x*v0.x + v0.y*v0.y + v0.z*v0.z + v0.w*v0.w
             + v1.x*v1.x + v1.y*v1.y + v1.z*v1.z + v1.w*v1.w;
#pragma unroll
    for (int off = 32; off > 0; off >>= 1) ss += __shfl_xor(ss, off);
    float sc = 1.0f / fmaxf(sqrtf(ss), 1e-12f);
    uint4 o;
    o.x = (unsigned)f2bf(v0.x*sc) | ((unsigned)f2bf(v0.y*sc) << 16);
    o.y = (unsigned)f2bf(v0.z*sc) | ((unsigned)f2bf(v0.w*sc) << 16);
    o.z = (unsigned)f2bf(v1.x*sc) | ((unsigned)f2bf(v1.y*sc) << 16);
    o.w = (unsigned)f2bf(v1.z*sc) | ((unsigned)f2bf(v1.w*sc) << 16);
    *((uint4*)(xnT + ((size_t)(lane << 9) + row) * 8)) = o;
}

__device__ __forceinline__ void g2ldsF(const float* g, float* l) {
    __builtin_amdgcn_global_load_lds(
        (const __attribute__((address_space(1))) void*)g,
        (__attribute__((address_space(3))) void*)l, 16, 0, 0);
}

// One block = 64 classes x all 512 rows. 8 waves; wave w owns rows
// [w*64, w*64+64) x cols [0,64) as 4x4 mfma_f32_16x16x32_bf16 frags.
// Per K-step ks (32 k): thread t (col=t>>3, kseg=t&7) stages 16 B of
// fp32 W via g2lds into bufF, repacks its 4 floats -> 4 bf16 into the
// frag-linear bufB slot ((kseg>>1)*64+col)*8+(kseg&1)*4, accumulating
// sumsq. One barrier/iter; all races separated by disjoint cur/nxt bufs.
__global__ __launch_bounds__(512, 4)
void gemm_fused_kernel(const float* __restrict__ W,
                       const ushort_t* __restrict__ xnT,
                       const int* __restrict__ y,
                       float* __restrict__ rowsumR,
                       float* __restrict__ tgt) {
    __shared__ float    bufF[2][2048];   // 16 KB fp32 staging (2 x 8 KB)
    __shared__ ushort_t bufB[2][2048];   // 8 KB bf16 frag-linear tiles
    __shared__ float    red[512];        // sumsq partials [col][kseg]
    __shared__ float    rnormS[64];      // 1/||W_col||
    __shared__ float    rowacc[512];     // per-row exp-sums

    int t    = threadIdx.x;
    int lane = t & 63;
    int w    = t >> 6;
    int lq   = lane >> 4;
    int lc   = lane & 15;
    int cn0  = blockIdx.x * 64;
    int col  = t >> 3;    // 0..63
    int kseg = t & 7;     // 4 fp32 each

    const float* gW = W + (size_t)(cn0 + col) * D_N + kseg * 4;

    // A-frag pointers into frag-linear xnT (256 B contiguous per lq
    // across the 16 lc lanes -> full-line L2 requests).
    const ushort_t* apT[4];
#pragma unroll
    for (int tm = 0; tm < 4; tm++)
        apT[tm] = xnT + ((size_t)lq * 512 + w * 64 + tm * 16 + lc) * 8;

    // prologue: stage ks=0, prefetch af(0)
    g2ldsF(gW, &bufF[0][t * 4]);
    short8 af[4];
#pragma unroll
    for (int tm = 0; tm < 4; tm++) af[tm] = *(const short8*)(apT[tm]);

    floatx4 acc[4][4];
#pragma unroll
    for (int i = 0; i < 4; i++)
#pragma unroll
        for (int j = 0; j < 4; j++) acc[i][j] = (floatx4){0.f, 0.f, 0.f, 0.f};
    float ssq = 0.0f;

    __syncthreads();  // drains prologue g2lds

    for (int ks = 0; ks < 16; ++ks) {
        int cur = ks & 1;
        if (ks < 15) g2ldsF(gW + (ks + 1) * 32, &bufF[cur ^ 1][t * 4]);

        // repack my 4 fp32 -> bf16 frag-linear + sumsq
        float4 wv = *(const float4*)&bufF[cur][t * 4];
        ssq += wv.x*wv.x + wv.y*wv.y + wv.z*wv.z + wv.w*wv.w;
        uint2 pk;
        pk.x = (unsigned)f2bf(wv.x) | ((unsigned)f2bf(wv.y) << 16);
        pk.y = (unsigned)f2bf(wv.z) | ((unsigned)f2bf(wv.w) << 16);
        *(uint2*)&bufB[cur][((kseg >> 1) * 64 + col) * 8 + (kseg & 1) * 4] = pk;

        short8 afn[4];
        if (ks < 15) {
#pragma unroll
            for (int tm = 0; tm < 4; tm++)
                afn[tm] = *(const short8*)(apT[tm] + (ks + 1) * 16384);
        }
        __syncthreads();  // bufB[cur] visible; g2lds(ks+1) drained

        short8 bfr[4];
#pragma unroll
        for (int tn = 0; tn < 4; tn++)
            bfr[tn] = *(const short8*)&bufB[cur][(lq * 64 + tn * 16 + lc) * 8];
#pragma unroll
        for (int tm = 0; tm < 4; tm++)
#pragma unroll
            for (int tn = 0; tn < 4; tn++)
                acc[tm][tn] = __builtin_amdgcn_mfma_f32_16x16x32_bf16(
                    af[tm], bfr[tn], acc[tm][tn], 0, 0, 0);
        if (ks < 15) {
#pragma unroll
            for (int tm = 0; tm < 4; tm++) af[tm] = afn[tm];
        }
    }

    // ---- reduce sumsq -> rnorm per col ----
    red[t] = ssq;
    __syncthreads();
    if (t < 64) {
        float s = 0.0f;
#pragma unroll
        for (int j = 0; j < 8; j++) s += red[t * 8 + j];
        rnormS[t] = 1.0f / fmaxf(sqrtf(s), 1e-12f);
    }
    __syncthreads();

    // ---- Epilogue. C/D layout: col = lane&15, row = lq*4 + reg. ----
    float rn[4];
#pragma unroll
    for (int tn = 0; tn < 4; tn++) rn[tn] = rnormS[tn * 16 + lc];
#pragma unroll
    for (int tm = 0; tm < 4; tm++) {
#pragma unroll
        for (int r = 0; r < 4; r++) {
            int lrow = w * 64 + tm * 16 + lq * 4 + r;  // 0..511, unique
            int yv   = y[lrow];
            float esum = 0.0f;
#pragma unroll
            for (int tn = 0; tn < 4; tn++) {
                int gcol = cn0 + tn * 16 + lc;
                float theta = acc[tm][tn][r] * rn[tn];
                if (gcol == yv) {
                    tgt[lrow] = theta;  // exactly one writer device-wide
                } else {
                    esum += __expf(S_SCALE * theta);
                }
            }
#pragma unroll
            for (int off = 1; off < 16; off <<= 1) esum += __shfl_xor(esum, off);
            if (lc == 0) rowacc[lrow] = esum;
        }
    }
    __syncthreads();
    atomicAdd(&rowsumR[(blockIdx.x & (NREP - 1)) * B_N + t], rowacc[t]);
}

__global__ void finalize_kernel(const float* __restrict__ rowsumR,
                                const float* __restrict__ tgt,
                                float* __restrict__ out) {
    __shared__ float red[256];
    int t = threadIdx.x;
    float s = 0.0f;
    for (int r = t; r < B_N; r += 256) {
        float rs = 0.0f;
#pragma unroll
        for (int i = 0; i < NREP; ++i) rs += rowsumR[i * B_N + r];
        float tv = tgt[r];
        tv = fminf(fmaxf(tv, -1.0f + EPS_C), 1.0f - EPS_C);
        float num = S_SCALE * cosf(acosf(tv) + MARGIN);
        float den = expf(num) + rs;
        s += num - logf(den);
    }
    red[t] = s;
    __syncthreads();
    for (int o = 128; o > 0; o >>= 1) {
        if (t < o) red[t] += red[t + o];
        __syncthreads();
    }
    if (t == 0) out[0] = -red[0] / (float)B_N;
}

extern "C" void kernel_launch(void* const* d_in, const int* in_sizes, int n_in,
                              void* d_out, int out_size, void* d_ws, size_t ws_size,
                              hipStream_t stream) {
    const float* x = (const float*)d_in[0];
    const int*   y = (const int*)d_in[1];
    const float* W = (const float*)d_in[2];
    float* out = (float*)d_out;

    char* ws = (char*)d_ws;
    ushort_t* xnT   = (ushort_t*)ws;                    // 512 KB (frag-linear)
    float* rowsumR  = (float*)(ws + 524288);            // 32 KB (16 replicas)
    float* tgt      = rowsumR + NREP * B_N;             // 2 KB

    xprep_kernel<<<129, 256, 0, stream>>>(x, xnT, rowsumR);
    gemm_fused_kernel<<<C_N / 64, 512, 0, stream>>>(W, xnT, y, rowsumR, tgt);
    finalize_kernel<<<1, 256, 0, stream>>>(rowsumR, tgt, out);
}

// Round 9
// 254.839 us; speedup vs baseline: 1.0621x; 1.0621x over previous
//
#include <hip/hip_runtime.h>

// ArcFace loss, MI355X. B=512, D=512, C=64000, s=64, m=0.5.
// R9: R8 architecture (stream W once through the K-loop; normalization
// folded into epilogue as theta = (x.W)*rsqrt(sumsq)), fixed:
//  - W staged via REGISTERS (not LDS): no bufF, no spills (R8's 116 MB
//    WRITE_SIZE was scratch), prefetch waits are fine-grained vmcnt at
//    first use instead of barrier vmcnt(0) drains.
//  - bf16 tile uses the R5-verified 0-conflict XOR layout
//    (kcl*512 + (col^kcl)*8)  [R8's 1.5M conflicts: swizzle was dropped].
//  - BK=64 per iter, 8 iters, ONE barrier per iter.

#define B_N 512
#define D_N 512
#define C_N 64000
#define S_SCALE 64.0f
#define MARGIN 0.5f
#define EPS_C 1e-7f
#define NREP 16

typedef unsigned short ushort_t;
typedef __attribute__((ext_vector_type(8))) short short8;   // 8 bf16 (4 VGPRs)
typedef __attribute__((ext_vector_type(4))) float floatx4;  // MFMA acc

__device__ __forceinline__ ushort_t f2bf(float f) {
    unsigned int u = __float_as_uint(f);
    u += 0x7fffu + ((u >> 16) & 1u);  // round-to-nearest-even
    return (ushort_t)(u >> 16);
}

// Normalize x rows -> bf16 in fragment-linear layout:
//   xnT element addr = (kc*512 + row)*8 + j,  kc = k/8 in [0,64), j = k%8.
// Blocks 0..127: 4 rows each. Block 128: zero rowsum replicas.
__global__ void xprep_kernel(const float* __restrict__ x,
                             ushort_t* __restrict__ xnT,
                             float* __restrict__ rowsumR) {
    int b = blockIdx.x;
    int t = threadIdx.x;
    if (b == 128) {
#pragma unroll
        for (int i = 0; i < NREP * B_N / 256; ++i)
            rowsumR[i * 256 + t] = 0.0f;
        return;
    }
    int row  = b * 4 + (t >> 6);
    int lane = t & 63;
    const float4* p = (const float4*)(x + (size_t)row * D_N);
    float4 v0 = p[lane * 2];
    float4 v1 = p[lane * 2 + 1];
    float ss = v0.x*v0.x + v0.y*v0.y + v0.z*v0.z + v0.w*v0.w
             + v1.x*v1.x + v1.y*v1.y + v1.z*v1.z + v1.w*v1.w;
#pragma unroll
    for (int off = 32; off > 0; off >>= 1) ss += __shfl_xor(ss, off);
    float sc = 1.0f / fmaxf(sqrtf(ss), 1e-12f);
    uint4 o;
    o.x = (unsigned)f2bf(v0.x*sc) | ((unsigned)f2bf(v0.y*sc) << 16);
    o.y = (unsigned)f2bf(v0.z*sc) | ((unsigned)f2bf(v0.w*sc) << 16);
    o.z = (unsigned)f2bf(v1.x*sc) | ((unsigned)f2bf(v1.y*sc) << 16);
    o.w = (unsigned)f2bf(v1.z*sc) | ((unsigned)f2bf(v1.w*sc) << 16);
    *((uint4*)(xnT + ((size_t)(lane << 9) + row) * 8)) = o;
}

// One block = 64 classes x all 512 rows. 8 waves; wave w owns rows
// [w*64, w*64+64) x cols [0,64) as 4x4 mfma_f32_16x16x32_bf16 frags.
// Per iter s (64 k): thread t (col=t>>3, kcl=t&7) owns W[col][s*64 +
// kcl*8 .. +7]: 32 B register load (prefetched during prior MFMA phase),
// cvt+pack -> one b128 ds_write to bufB[cur] at kcl*512+(col^kcl)*8,
// sumsq accumulated in-register. One __syncthreads per iter.
__global__ __launch_bounds__(512, 4)
void gemm_fused_kernel(const float* __restrict__ W,
                       const ushort_t* __restrict__ xnT,
                       const int* __restrict__ y,
                       float* __restrict__ rowsumR,
                       float* __restrict__ tgt) {
    __shared__ ushort_t bufB[2][4096];   // 2 x 8 KB bf16 frag tiles
    __shared__ float    rnormS[64];      // 1/||W_col||
    __shared__ float    rowacc[512];     // per-row exp-sums

    int t    = threadIdx.x;
    int lane = t & 63;
    int w    = t >> 6;
    int lq   = lane >> 4;
    int lc   = lane & 15;
    int cn0  = blockIdx.x * 64;
    int col  = t >> 3;    // 0..63
    int kcl  = t & 7;     // 8-elem k-chunk within the 64-k step

    const float4* gW = (const float4*)(W + (size_t)(cn0 + col) * D_N + kcl * 8);
    // per iter s: chunks at gW + s*16 (+0 and +1)

    const ushort_t* apT[4];
#pragma unroll
    for (int tm = 0; tm < 4; tm++)
        apT[tm] = xnT + ((size_t)lq * 512 + w * 64 + tm * 16 + lc) * 8;

    floatx4 acc[4][4];
#pragma unroll
    for (int i = 0; i < 4; i++)
#pragma unroll
        for (int j = 0; j < 4; j++) acc[i][j] = (floatx4){0.f, 0.f, 0.f, 0.f};
    float ssq = 0.0f;

    // prologue: W chunk for s=0 into registers
    float4 w0 = gW[0];
    float4 w1 = gW[1];

    for (int s = 0; s < 8; ++s) {
        int cur = s & 1;
        // ---- pack: registers -> bf16 frag-linear LDS (+ sumsq) ----
        ssq += w0.x*w0.x + w0.y*w0.y + w0.z*w0.z + w0.w*w0.w
             + w1.x*w1.x + w1.y*w1.y + w1.z*w1.z + w1.w*w1.w;
        uint4 pk;
        pk.x = (unsigned)f2bf(w0.x) | ((unsigned)f2bf(w0.y) << 16);
        pk.y = (unsigned)f2bf(w0.z) | ((unsigned)f2bf(w0.w) << 16);
        pk.z = (unsigned)f2bf(w1.x) | ((unsigned)f2bf(w1.y) << 16);
        pk.w = (unsigned)f2bf(w1.z) | ((unsigned)f2bf(w1.w) << 16);
        *(uint4*)&bufB[cur][kcl * 512 + (col ^ kcl) * 8] = pk;
        __syncthreads();  // bufB[cur] visible (nothing else outstanding)

        // ---- issue next-iter W loads; consumed at next pack ----
        if (s < 7) {
            w0 = gW[(s + 1) * 16];
            w1 = gW[(s + 1) * 16 + 1];
        }

        // ---- 2 x 32-k MFMA halves; af from L2 xnT, bfr from bufB ----
#pragma unroll
        for (int h = 0; h < 2; ++h) {
            short8 af[4], bfr[4];
#pragma unroll
            for (int tm = 0; tm < 4; tm++)
                af[tm] = *(const short8*)(apT[tm] + (s * 2 + h) * 16384);
            int kb = h * 4 + lq;
#pragma unroll
            for (int tn = 0; tn < 4; tn++)
                bfr[tn] = *(const short8*)
                    &bufB[cur][kb * 512 + ((tn * 16 + lc) ^ kb) * 8];
#pragma unroll
            for (int tm = 0; tm < 4; tm++)
#pragma unroll
                for (int tn = 0; tn < 4; tn++)
                    acc[tm][tn] = __builtin_amdgcn_mfma_f32_16x16x32_bf16(
                        af[tm], bfr[tn], acc[tm][tn], 0, 0, 0);
        }
        __syncthreads();  // all reads of bufB[cur] done before s+2 pack
    }

    // ---- per-col rnorm from in-register sumsq (8 threads per col) ----
#pragma unroll
    for (int off = 1; off < 8; off <<= 1) ssq += __shfl_xor(ssq, off);
    if (kcl == 0) rnormS[col] = 1.0f / fmaxf(sqrtf(ssq), 1e-12f);
    __syncthreads();

    // ---- Epilogue. C/D layout: col = lane&15, row = lq*4 + reg. ----
    float rn[4];
#pragma unroll
    for (int tn = 0; tn < 4; tn++) rn[tn] = rnormS[tn * 16 + lc];
#pragma unroll
    for (int tm = 0; tm < 4; tm++) {
#pragma unroll
        for (int r = 0; r < 4; r++) {
            int lrow = w * 64 + tm * 16 + lq * 4 + r;  // 0..511, unique
            int yv   = y[lrow];
            float esum = 0.0f;
#pragma unroll
            for (int tn = 0; tn < 4; tn++) {
                int gcol = cn0 + tn * 16 + lc;
                float theta = acc[tm][tn][r] * rn[tn];
                if (gcol == yv) {
                    tgt[lrow] = theta;  // exactly one writer device-wide
                } else {
                    esum += __expf(S_SCALE * theta);
                }
            }
#pragma unroll
            for (int off = 1; off < 16; off <<= 1) esum += __shfl_xor(esum, off);
            if (lc == 0) rowacc[lrow] = esum;
        }
    }
    __syncthreads();
    atomicAdd(&rowsumR[(blockIdx.x & (NREP - 1)) * B_N + t], rowacc[t]);
}

__global__ void finalize_kernel(const float* __restrict__ rowsumR,
                                const float* __restrict__ tgt,
                                float* __restrict__ out) {
    __shared__ float red[256];
    int t = threadIdx.x;
    float s = 0.0f;
    for (int r = t; r < B_N; r += 256) {
        float rs = 0.0f;
#pragma unroll
        for (int i = 0; i < NREP; ++i) rs += rowsumR[i * B_N + r];
        float tv = tgt[r];
        tv = fminf(fmaxf(tv, -1.0f + EPS_C), 1.0f - EPS_C);
        float num = S_SCALE * cosf(acosf(tv) + MARGIN);
        float den = expf(num) + rs;
        s += num - logf(den);
    }
    red[t] = s;
    __syncthreads();
    for (int o = 128; o > 0; o >>= 1) {
        if (t < o) red[t] += red[t + o];
        __syncthreads();
    }
    if (t == 0) out[0] = -red[0] / (float)B_N;
}

extern "C" void kernel_launch(void* const* d_in, const int* in_sizes, int n_in,
                              void* d_out, int out_size, void* d_ws, size_t ws_size,
                              hipStream_t stream) {
    const float* x = (const float*)d_in[0];
    const int*   y = (const int*)d_in[1];
    const float* W = (const float*)d_in[2];
    float* out = (float*)d_out;

    char* ws = (char*)d_ws;
    ushort_t* xnT   = (ushort_t*)ws;                    // 512 KB (frag-linear)
    float* rowsumR  = (float*)(ws + 524288);            // 32 KB (16 replicas)
    float* tgt      = rowsumR + NREP * B_N;             // 2 KB

    xprep_kernel<<<129, 256, 0, stream>>>(x, xnT, rowsumR);
    gemm_fused_kernel<<<C_N / 64, 512, 0, stream>>>(W, xnT, y, rowsumR, tgt);
    finalize_kernel<<<1, 256, 0, stream>>>(rowsumR, tgt, out);
}